// Round 10
// baseline (792.190 us; speedup 1.0000x reference)
//
#include <hip/hip_runtime.h>

#define EPSF 1e-5f

typedef _Float16 h2f  __attribute__((ext_vector_type(2)));
typedef _Float16 h8   __attribute__((ext_vector_type(8)));
typedef float    f32x4 __attribute__((ext_vector_type(4)));

#if defined(__has_builtin)
#if __has_builtin(__builtin_amdgcn_fdot2)
#define HAVE_FDOT2 1
#endif
#endif

__device__ __forceinline__ float fsig(float x){ return 1.0f/(1.0f+__expf(-x)); }
__device__ __forceinline__ float ftanh(float x){
  float e = __expf(2.f*x);
  float r = (e-1.f)/(e+1.f);
  return (x > 15.f) ? 1.f : ((x < -15.f) ? -1.f : r);
}
__device__ __forceinline__ int pkf(float lo, float hi){
  return __builtin_bit_cast(int, __builtin_amdgcn_cvt_pkrtz(lo, hi));
}
__device__ __forceinline__ int4 mk4(const float* p){
  return make_int4(pkf(p[0],p[1]),pkf(p[2],p[3]),pkf(p[4],p[5]),pkf(p[6],p[7]));
}
__device__ __forceinline__ float dot2(int w, int x, float acc){
#ifdef HAVE_FDOT2
  return __builtin_amdgcn_fdot2(__builtin_bit_cast(h2f, w),
                                __builtin_bit_cast(h2f, x), acc, false);
#else
  h2f a = __builtin_bit_cast(h2f, w), b = __builtin_bit_cast(h2f, x);
  return acc + (float)a[0]*(float)b[0] + (float)a[1]*(float)b[1];
#endif
}
__device__ __forceinline__ int rl_i(int v, int l){ return __builtin_amdgcn_readlane(v, l); }
__device__ __forceinline__ float rl_f(float v, int l){
  return __int_as_float(__builtin_amdgcn_readlane(__float_as_int(v), l));
}
#define MFMA(A,B,C) __builtin_amdgcn_mfma_f32_16x16x32_f16( \
    __builtin_bit_cast(h8,(A)), __builtin_bit_cast(h8,(B)), (C), 0,0,0)
// light barrier: drain LDS only; global loads/stores stay in flight
#define BAR() do{ asm volatile("s_waitcnt lgkmcnt(0)" ::: "memory"); __builtin_amdgcn_s_barrier(); }while(0)

// ---------------------------------------------------------------------------
// Kernel 1: msum[t] = sum_{b,n} masks[b,t,n] + EPS   (one block per t)
// ---------------------------------------------------------------------------
__global__ void msum_kernel(const float* __restrict__ masks, float* __restrict__ msum){
  const int t   = blockIdx.x;
  const int tid = threadIdx.x;
  const int b0  = tid >> 3;
  const int n4  = (tid & 7) << 2;
  float s = 0.f;
  #pragma unroll 4
  for (int i = 0; i < 32; ++i) {
    const int b = b0 + (i << 5);
    const float4 v = *reinterpret_cast<const float4*>(masks + ((size_t)b*256 + t)*32 + n4);
    s += v.x + v.y + v.z + v.w;
  }
  __shared__ float red[256];
  red[tid] = s; __syncthreads();
  for (int off = 128; off > 0; off >>= 1) {
    if (tid < off) red[tid] += red[tid + off];
    __syncthreads();
  }
  if (tid == 0) msum[t] = red[0] + EPSF;
}

// ---------------------------------------------------------------------------
// Kernel 2: persistent RNN. 256 blocks x 512 threads, 4 batch elems / block.
// Waves 0-3 = chain (elem wv), weights VGPR-resident, NO LDS weight loads,
// no gamma_h/alpha matvecs (precomputed). Waves 4-7 = all MFMA: gate GEMM
// (wave=gate, activation in-wave) + gamma_h_lin(t+1) + alpha(t+1) from
// double-buffered future word region fb[p] (inputs prefetched 2 deep).
// 2 light barriers/step.
// ---------------------------------------------------------------------------
__global__ __launch_bounds__(512, 1) void rits_kernel(
  const float* __restrict__ values, const float* __restrict__ masks,
  const float* __restrict__ deltas, const float* __restrict__ labels,
  const float* __restrict__ is_train,
  const float* __restrict__ td_h_W, const float* __restrict__ td_h_b,
  const float* __restrict__ td_x_W, const float* __restrict__ td_x_b,
  const float* __restrict__ hist_W, const float* __restrict__ hist_b,
  const float* __restrict__ feat_W, const float* __restrict__ feat_b,
  const float* __restrict__ wc_W,  const float* __restrict__ wc_b,
  const float* __restrict__ W_ih,  const float* __restrict__ W_hh,
  const float* __restrict__ b_ih,  const float* __restrict__ b_hh,
  const float* __restrict__ out_W, const float* __restrict__ out_b,
  const float* __restrict__ msum,
  float* __restrict__ xl_acc, float* __restrict__ bce_acc,
  float* __restrict__ predictions, float* __restrict__ imps)
{
  // rows stride 52 ints -> rows 0..3 land on distinct bank quads (52%32 -> 0,20,8,28)
  __shared__ __align__(16) int  cur[4][52];     // [e][ ccw 0-15 | hw 16-47 ]
  __shared__ __align__(16) int  fb[2][4][52];   // [p][e][ dw 0-15 | gxw 16-31 | mw 32-47 ]
  __shared__ float sB[4][64];    // gamma_h linear (pre-exp), for step being entered
  __shared__ float sAl[4][32];   // alpha, for step being entered
  __shared__ float gp[4][256];   // ACTIVATED gates
  __shared__ float msum_l[256];  // 1/msum[t]

  const int tid = threadIdx.x;
  const int b   = blockIdx.x;
  const int wv  = tid >> 6;           // 0..7
  const int ln  = tid & 63;
  const int c16 = ln & 15;
  const int kg  = ln >> 4;
  const int arow= ln & 15;
  const bool chain = (wv < 4);
  const int me  = wv & 3;
  const int wq  = wv - 4;             // gate id for GEMM waves (0=i,1=f,2=g,3=o)
  const int b2  = (b << 2) | me;

  if (tid < 256) msum_l[tid] = 1.f / msum[tid];
  { float* g = (float*)gp; g[tid] = 0.f; g[tid+512] = 0.f; }   // F(t=0) -> c=h=0
  if (tid < 256) ((float*)sB)[tid] = 0.f;                      // h=0, value moot

  // ---- VGPR weight fragments ----
  // chain waves: hist row (packed) + feat row (fp32, diag 0) + diag/bias regs
  int4  pkCr[8];
  float wz[32];
  float histb_r=0.f, featb_r=0.f, tdxd_r=0.f, tdxb_r=0.f, ow_r=0.f;
  // GEMM waves: gates 16 int4 + gamma_h 1 int4 + alpha 2 int4 + biases
  int4  fG[4][4], fA[2];
  int4  fGh = make_int4(0,0,0,0);
  float gb[4] = {0,0,0,0};
  float ghb=0.f, alb=0.f;

  if (chain){
    const int nr = ln & 31;
    #pragma unroll
    for (int g = 0; g < 8; ++g) pkCr[g] = mk4(hist_W + nr*64 + 8*g);
    #pragma unroll
    for (int k = 0; k < 32; ++k) wz[k] = (k==nr) ? 0.f : feat_W[nr*32 + k];
    histb_r = hist_b[nr]; featb_r = feat_b[nr];
    tdxd_r  = td_x_W[nr*33]; tdxb_r = td_x_b[nr];
    ow_r    = out_W[ln];
  } else {
    #pragma unroll
    for (int nt = 0; nt < 4; ++nt){
      const int col = (wq << 6) + (nt << 4) + c16;
      fG[nt][0] = mk4(W_ih + (size_t)col*64 + kg*8);
      fG[nt][1] = mk4(W_ih + (size_t)col*64 + 32 + kg*8);
      fG[nt][2] = mk4(W_hh + (size_t)col*64 + kg*8);
      fG[nt][3] = mk4(W_hh + (size_t)col*64 + 32 + kg*8);
      gb[nt]    = b_ih[col] + b_hh[col];
    }
    const int colj = (wq << 4) + c16;                // gamma_h tile wq
    fGh = mk4(td_h_W + colj*32 + kg*8);
    ghb = td_h_b[colj];
    if (wq < 2){                                     // alpha tiles 0,1
      const int coln = (wq << 4) + c16;
      fA[0] = mk4(wc_W + coln*64 + kg*8);
      fA[1] = mk4(wc_W + coln*64 + 32 + kg*8);
      alb   = wc_b[coln];
    }
  }

  // ---- chain state + 2-deep input pipeline ----
  const int i0 = (2*ln) & 63, i1 = (2*ln+1) & 63;
  float xc_r=0.f, mc_r=0.f;              // step t inputs
  float lx=0.f, lm=0.f, ld=0.f;          // step t+1 inputs (inbound)
  float h_reg=0.f, c_reg=0.f, loss_acc=0.f;
  if (chain){
    float d0 = 0.f;
    if (ln < 32){
      const size_t base = (size_t)b2*8192 + ln;
      xc_r = values[base]; mc_r = masks[base]; d0 = deltas[base];
      lx = values[base+32]; lm = masks[base+32]; ld = deltas[base+32];
    }
    // fb[0] <- (dw, gxw, mw)(t=0)
    const float gx0 = __expf(-fmaxf(fmaf(d0, tdxd_r, tdxb_r), 0.f));
    const int dw0 = pkf(__shfl(d0,  i0), __shfl(d0,  i1));
    const int gw0 = pkf(__shfl(gx0, i0), __shfl(gx0, i1));
    const int mw0 = pkf(__shfl(mc_r,i0), __shfl(mc_r,i1));
    if (ln < 16){ fb[0][me][ln]=dw0; fb[0][me][16+ln]=gw0; fb[0][me][32+ln]=mw0; }
  }
  __syncthreads();
  // ---- prologue E: alpha(0) from fb[0] ----
  if (!chain && wq < 2){
    int4 a0 = make_int4(0,0,0,0), a1 = make_int4(0,0,0,0);
    if (arow < 4){
      a0 = *(const int4*)&fb[0][arow][16 + kg*4];
      a1 = *(const int4*)&fb[0][arow][32 + kg*4];
    }
    f32x4 acc = {alb, alb, alb, alb};
    acc = MFMA(a0, fA[0], acc);
    acc = MFMA(a1, fA[1], acc);
    if (kg == 0){
      #pragma unroll
      for (int e = 0; e < 4; ++e) sAl[e][(wq<<4)|c16] = acc[e];
    }
  }
  __syncthreads();

  for (int t = 0; t < 256; ++t){
    if (chain){
      // ---- F(t-1) + decay + chain transforms ----
      const float gi = gp[me][ln],      gf = gp[me][64+ln];
      const float gg = gp[me][128+ln],  go = gp[me][192+ln];
      const float sb = sB[me][ln];
      const float al = sAl[me][ln & 31];
      c_reg = gf*c_reg + gi*gg;
      h_reg = go * ftanh(c_reg);
      h_reg *= __expf(-fmaxf(sb, 0.f));
      const int hw = pkf(__shfl(h_reg, i0), __shfl(h_reg, i1));  // h pairs, words 0..31
      if (ln < 32) cur[me][16+ln] = hw;
      // x_h (K=64 packed dot2, VGPR weights)
      float a0 = histb_r, a1 = 0.f, a2 = 0.f, a3 = 0.f;
      #pragma unroll
      for (int g = 0; g < 8; ++g){
        const int4 w = pkCr[g];
        a0 = dot2(w.x, rl_i(hw, 4*g+0), a0);
        a1 = dot2(w.y, rl_i(hw, 4*g+1), a1);
        a2 = dot2(w.z, rl_i(hw, 4*g+2), a2);
        a3 = dot2(w.w, rl_i(hw, 4*g+3), a3);
      }
      const float xh_v  = (a0+a1)+(a2+a3);
      const float x_c_v = mc_r*xc_r + (1.f-mc_r)*xh_v;
      // z (K=32 fp32 readlane of x_c directly -- no pack)
      float z0 = featb_r, z1 = 0.f, z2 = 0.f, z3 = 0.f;
      #pragma unroll
      for (int k = 0; k < 32; k += 4){
        z0 = fmaf(rl_f(x_c_v, k+0), wz[k+0], z0);
        z1 = fmaf(rl_f(x_c_v, k+1), wz[k+1], z1);
        z2 = fmaf(rl_f(x_c_v, k+2), wz[k+2], z2);
        z3 = fmaf(rl_f(x_c_v, k+3), wz[k+3], z3);
      }
      const float z  = (z0+z1)+(z2+z3);
      const float chv= al*z + (1.f-al)*xh_v;
      loss_acc += (fabsf(xc_r-xh_v)+fabsf(xc_r-z)+fabsf(xc_r-chv))*mc_r*msum_l[t];
      const float ccv = mc_r*xc_r + (1.f-mc_r)*chv;
      if (ln < 32) imps[(size_t)b2*8192 + (size_t)t*32 + ln] = ccv;
      const int ccw = pkf(__shfl(ccv, i0), __shfl(ccv, i1));
      if (ln < 16) cur[me][ln] = ccw;
      // future region (t+1): off critical path
      const float gxn = __expf(-fmaxf(fmaf(ld, tdxd_r, tdxb_r), 0.f));
      const int dwn = pkf(__shfl(ld,  i0), __shfl(ld,  i1));
      const int gwn = pkf(__shfl(gxn, i0), __shfl(gxn, i1));
      const int mwn = pkf(__shfl(lm,  i0), __shfl(lm,  i1));
      if (ln < 16){
        const int p1 = (t+1) & 1;
        fb[p1][me][ln]=dwn; fb[p1][me][16+ln]=gwn; fb[p1][me][32+ln]=mwn;
      }
      // rotate + prefetch t+2
      xc_r = lx; mc_r = lm;
      if (ln < 32 && t < 254){
        const size_t base = (size_t)b2*8192 + (size_t)(t+2)*32 + ln;
        lx = values[base]; lm = masks[base]; ld = deltas[base];
      }
    }

    BAR();   // cur, fb[p1] visible

    if (!chain){
      const int p0 = t & 1, p1 = p0 ^ 1;
      int4 Acc = make_int4(0,0,0,0), Am = Acc, Ah0 = Acc, Ah1 = Acc;
      int4 Agh = Acc, Aa0 = Acc, Aa1 = Acc;
      if (arow < 4){
        Acc = *(const int4*)&cur[arow][kg*4];
        Ah0 = *(const int4*)&cur[arow][16 + kg*4];
        Ah1 = *(const int4*)&cur[arow][32 + kg*4];
        Am  = *(const int4*)&fb[p0][arow][32 + kg*4];
        Agh = *(const int4*)&fb[p1][arow][kg*4];
        Aa0 = *(const int4*)&fb[p1][arow][16 + kg*4];
        Aa1 = *(const int4*)&fb[p1][arow][32 + kg*4];
      }
      f32x4 acc[4];
      #pragma unroll
      for (int nt = 0; nt < 4; ++nt) acc[nt] = (f32x4){gb[nt],gb[nt],gb[nt],gb[nt]};
      #pragma unroll
      for (int nt = 0; nt < 4; ++nt) acc[nt] = MFMA(Acc, fG[nt][0], acc[nt]);
      #pragma unroll
      for (int nt = 0; nt < 4; ++nt) acc[nt] = MFMA(Am,  fG[nt][1], acc[nt]);
      #pragma unroll
      for (int nt = 0; nt < 4; ++nt) acc[nt] = MFMA(Ah0, fG[nt][2], acc[nt]);
      #pragma unroll
      for (int nt = 0; nt < 4; ++nt) acc[nt] = MFMA(Ah1, fG[nt][3], acc[nt]);
      f32x4 accg = {ghb, ghb, ghb, ghb};
      accg = MFMA(Agh, fGh, accg);
      f32x4 acca = {alb, alb, alb, alb};
      if (wq < 2){ acca = MFMA(Aa0, fA[0], acca); acca = MFMA(Aa1, fA[1], acca); }
      if (kg == 0){
        #pragma unroll
        for (int nt = 0; nt < 4; ++nt){
          const int col = (wq<<6) + (nt<<4) + c16;
          #pragma unroll
          for (int e = 0; e < 4; ++e){
            const float v = acc[nt][e];
            gp[e][col] = (wq == 2) ? ftanh(v) : fsig(v);
          }
        }
        #pragma unroll
        for (int e = 0; e < 4; ++e) sB[e][(wq<<4)|c16] = accg[e];
        if (wq < 2){
          #pragma unroll
          for (int e = 0; e < 4; ++e) sAl[e][(wq<<4)|c16] = acca[e];
        }
      }
    }

    BAR();   // gp, sB, sAl visible
  }

  // ---- epilogue: F(255), prediction, BCE, loss reduce (chain waves) ----
  if (chain){
    const float gi = gp[me][ln],     gf = gp[me][64+ln];
    const float gg = gp[me][128+ln], go = gp[me][192+ln];
    c_reg = gf*c_reg + gi*gg;
    h_reg = go * ftanh(c_reg);

    float p = h_reg * ow_r;
    p += __shfl_xor(p,32); p += __shfl_xor(p,16); p += __shfl_xor(p,8);
    p += __shfl_xor(p,4);  p += __shfl_xor(p,2);  p += __shfl_xor(p,1);

    float l = loss_acc;   // nonzero only on ln<32
    l += __shfl_xor(l,32); l += __shfl_xor(l,16); l += __shfl_xor(l,8);
    l += __shfl_xor(l,4);  l += __shfl_xor(l,2);  l += __shfl_xor(l,1);

    if (ln == 0){
      atomicAdd(xl_acc, l);
      const float y = p + out_b[0];
      predictions[b2] = fsig(y);
      const float lab = labels[b2];
      const float it  = is_train[b2];
      const float mx  = fmaxf(-y, 0.f);
      const float bce = y - y*lab + mx + __logf(__expf(-mx) + __expf(-y - mx));
      atomicAdd(bce_acc, bce * it);
    }
  }
}

// ---------------------------------------------------------------------------
// Kernel 3: finalize loss scalar
// ---------------------------------------------------------------------------
__global__ void final_kernel(const float* __restrict__ is_train,
                             const float* __restrict__ ws,
                             float* __restrict__ out){
  const int tid = threadIdx.x;
  __shared__ float red[256];
  red[tid] = is_train[tid] + is_train[tid+256] + is_train[tid+512] + is_train[tid+768];
  __syncthreads();
  for (int off = 128; off > 0; off >>= 1){
    if (tid < off) red[tid] += red[tid + off];
    __syncthreads();
  }
  if (tid == 0){
    const float yl = ws[1] / (red[0] + EPSF);
    out[0] = ws[0] / 256.0f + 0.1f * yl;
  }
}

extern "C" void kernel_launch(void* const* d_in, const int* in_sizes, int n_in,
                              void* d_out, int out_size, void* d_ws, size_t ws_size,
                              hipStream_t stream){
  const float* values   = (const float*)d_in[0];
  const float* masks    = (const float*)d_in[1];
  const float* deltas   = (const float*)d_in[2];
  const float* labels   = (const float*)d_in[5];
  const float* is_train = (const float*)d_in[6];
  const float* td_h_W   = (const float*)d_in[7];
  const float* td_h_b   = (const float*)d_in[8];
  const float* td_x_W   = (const float*)d_in[9];
  const float* td_x_b   = (const float*)d_in[10];
  const float* hist_W   = (const float*)d_in[11];
  const float* hist_b   = (const float*)d_in[12];
  const float* feat_W   = (const float*)d_in[13];
  const float* feat_b   = (const float*)d_in[14];
  const float* wc_W     = (const float*)d_in[15];
  const float* wc_b     = (const float*)d_in[16];
  const float* W_ih     = (const float*)d_in[17];
  const float* W_hh     = (const float*)d_in[18];
  const float* b_ih     = (const float*)d_in[19];
  const float* b_hh     = (const float*)d_in[20];
  const float* out_W    = (const float*)d_in[21];
  const float* out_b    = (const float*)d_in[22];

  float* out = (float*)d_out;                 // [0]=loss, [1..1025)=preds, [1025..)=imps
  float* ws  = (float*)d_ws;                  // [0]=xl_sum, [1]=bce_sum, [2..258)=msum

  hipMemsetAsync(ws, 0, 2*sizeof(float), stream);
  msum_kernel<<<256, 256, 0, stream>>>(masks, ws + 2);
  rits_kernel<<<256, 512, 0, stream>>>(values, masks, deltas, labels, is_train,
      td_h_W, td_h_b, td_x_W, td_x_b, hist_W, hist_b, feat_W, feat_b,
      wc_W, wc_b, W_ih, W_hh, b_ih, b_hh, out_W, out_b,
      ws + 2, ws + 0, ws + 1, out + 1, out + 1 + 1024);
  final_kernel<<<1, 256, 0, stream>>>(is_train, ws, out);
}

// Round 11
// 458.202 us; speedup vs baseline: 1.7289x; 1.7289x over previous
//
#include <hip/hip_runtime.h>

#define EPSF 1e-5f

typedef _Float16 h2f  __attribute__((ext_vector_type(2)));
typedef _Float16 h8   __attribute__((ext_vector_type(8)));
typedef float    f32x4 __attribute__((ext_vector_type(4)));

#if defined(__has_builtin)
#if __has_builtin(__builtin_amdgcn_fdot2)
#define HAVE_FDOT2 1
#endif
#endif

__device__ __forceinline__ float fsig(float x){ return 1.0f/(1.0f+__expf(-x)); }
__device__ __forceinline__ float ftanh(float x){
  float e = __expf(2.f*x);
  float r = (e-1.f)/(e+1.f);
  return (x > 15.f) ? 1.f : ((x < -15.f) ? -1.f : r);
}
__device__ __forceinline__ int pkf(float lo, float hi){
  return __builtin_bit_cast(int, __builtin_amdgcn_cvt_pkrtz(lo, hi));
}
__device__ __forceinline__ int4 mk4(const float* p){
  return make_int4(pkf(p[0],p[1]),pkf(p[2],p[3]),pkf(p[4],p[5]),pkf(p[6],p[7]));
}
__device__ __forceinline__ float dot2(int w, int x, float acc){
#ifdef HAVE_FDOT2
  return __builtin_amdgcn_fdot2(__builtin_bit_cast(h2f, w),
                                __builtin_bit_cast(h2f, x), acc, false);
#else
  h2f a = __builtin_bit_cast(h2f, w), b = __builtin_bit_cast(h2f, x);
  return acc + (float)a[0]*(float)b[0] + (float)a[1]*(float)b[1];
#endif
}
__device__ __forceinline__ int rl_i(int v, int l){ return __builtin_amdgcn_readlane(v, l); }
__device__ __forceinline__ float rl_f(float v, int l){
  return __int_as_float(__builtin_amdgcn_readlane(__float_as_int(v), l));
}
// light barrier: order LDS only; global loads/stores stay in flight
#define BAR() do{ asm volatile("s_waitcnt lgkmcnt(0)" ::: "memory"); __builtin_amdgcn_s_barrier(); }while(0)

// ---------------------------------------------------------------------------
// Kernel 1: msum[t] = sum_{b,n} masks[b,t,n] + EPS   (one block per t)
// ---------------------------------------------------------------------------
__global__ void msum_kernel(const float* __restrict__ masks, float* __restrict__ msum){
  const int t   = blockIdx.x;
  const int tid = threadIdx.x;
  const int b0  = tid >> 3;
  const int n4  = (tid & 7) << 2;
  float s = 0.f;
  #pragma unroll 4
  for (int i = 0; i < 32; ++i) {
    const int b = b0 + (i << 5);
    const float4 v = *reinterpret_cast<const float4*>(masks + ((size_t)b*256 + t)*32 + n4);
    s += v.x + v.y + v.z + v.w;
  }
  __shared__ float red[256];
  red[tid] = s; __syncthreads();
  for (int off = 128; off > 0; off >>= 1) {
    if (tid < off) red[tid] += red[tid + off];
    __syncthreads();
  }
  if (tid == 0) msum[t] = red[0] + EPSF;
}

// ---------------------------------------------------------------------------
// Kernel 2: persistent RNN. 256 blocks x 512 threads, 4 batch elems / block.
// Round-7 skeleton (chains on waves 0-3, gate GEMM via MFMA on all 8 waves,
// 2 light barriers) with 3 deltas: (1) chain weights VGPR-resident (no LDS
// weight loads), (2) feat z-matvec via fp32 readlane (no xcw pack; aw pack
// hoisted off the critical path), (3) inp_s rows padded to 84 words (rows
// 0-3 on distinct banks -> conflict-free E A-fragment reads).
// ---------------------------------------------------------------------------
__global__ __launch_bounds__(512, 1) void rits_kernel(
  const float* __restrict__ values, const float* __restrict__ masks,
  const float* __restrict__ deltas, const float* __restrict__ labels,
  const float* __restrict__ is_train,
  const float* __restrict__ td_h_W, const float* __restrict__ td_h_b,
  const float* __restrict__ td_x_W, const float* __restrict__ td_x_b,
  const float* __restrict__ hist_W, const float* __restrict__ hist_b,
  const float* __restrict__ feat_W, const float* __restrict__ feat_b,
  const float* __restrict__ wc_W,  const float* __restrict__ wc_b,
  const float* __restrict__ W_ih,  const float* __restrict__ W_hh,
  const float* __restrict__ b_ih,  const float* __restrict__ b_hh,
  const float* __restrict__ out_W, const float* __restrict__ out_b,
  const float* __restrict__ msum,
  float* __restrict__ xl_acc, float* __restrict__ bce_acc,
  float* __restrict__ predictions, float* __restrict__ imps)
{
  // [e][ ccw 0..15 | mw 16..31 | hw 32..63 ] ; stride 84 (84%32=20) ->
  // rows 0..3 land on distinct banks for same-word reads.
  __shared__ __align__(16) int  inp_s[4][84];
  __shared__ float gp[4][256];    // [elem][gate row]
  __shared__ float msum_l[256];   // 1/msum[t]

  const int tid = threadIdx.x;
  const int b   = blockIdx.x;
  const int wv  = tid >> 6;          // 0..7
  const int ln  = tid & 63;
  const bool chain = (wv < 4);
  const int me  = wv & 3;
  const int b2  = (b << 2) | me;

  if (tid < 256) msum_l[tid] = 1.0f / msum[tid];

  // ---- per-thread gate B-fragments (all 8 waves): 2 n-tiles x 4 k-steps ----
  int4 Wb[2][4];
  const int kg = ln >> 4;
  #pragma unroll
  for (int nt = 0; nt < 2; ++nt){
    const int col = (wv << 5) + (nt << 4) + (ln & 15);
    #pragma unroll
    for (int ks = 0; ks < 4; ++ks){
      const int k0 = (ks << 5) + (kg << 3);
      const float* src = (k0 < 64) ? (W_ih + (size_t)col*64 + k0)
                                   : (W_hh + (size_t)col*64 + (k0 - 64));
      Wb[nt][ks] = make_int4(pkf(src[0],src[1]), pkf(src[2],src[3]),
                             pkf(src[4],src[5]), pkf(src[6],src[7]));
    }
  }
  const int col0 = (wv << 5) + (ln & 15);
  const float bs0 = b_ih[col0]      + b_hh[col0];
  const float bs1 = b_ih[col0 + 16] + b_hh[col0 + 16];

  // ---- chain-wave VGPR weights + registers ----
  int4  fB[4];      // td_h_W row ln (K=32)
  int4  fC[8];      // hist_W row (ln&31) (K=64)
  int4  fDa[8];     // wc_W row (ln&31) (K=64, [gx|m])
  float wz[32];     // feat_W row (ln&31), fp32, diag 0
  float thb_r=0.f, tdxd_r=0.f, tdxb_r=0.f, histb_r=0.f, featb_r=0.f, wcb_r=0.f;
  float xv=0.f, mv=0.f, dv=0.f;
  if (chain){
    const int nr = ln & 31;
    #pragma unroll
    for (int g = 0; g < 4; ++g) fB[g] = mk4(td_h_W + ln*32 + 8*g);
    #pragma unroll
    for (int g = 0; g < 8; ++g) fC[g] = mk4(hist_W + nr*64 + 8*g);
    #pragma unroll
    for (int g = 0; g < 8; ++g) fDa[g] = mk4(wc_W + nr*64 + 8*g);
    #pragma unroll
    for (int k = 0; k < 32; ++k) wz[k] = (k==nr) ? 0.f : feat_W[nr*32 + k];
    thb_r = td_h_b[ln];
    if (ln < 32){
      tdxd_r  = td_x_W[ln*33];
      tdxb_r  = td_x_b[ln];
      histb_r = hist_b[ln];
      featb_r = feat_b[ln];
      wcb_r   = wc_b[ln];
      const size_t base = (size_t)b2*8192 + ln;
      xv = values[base]; mv = masks[base]; dv = deltas[base];
    }
  }
  float h_reg = 0.f, c_reg = 0.f, loss_acc = 0.f;

  __syncthreads();

  for (int t = 0; t < 256; ++t){
    // ---- chain A-D ----
    if (chain){
      const float x_cur = xv, m_cur = mv, d_cur = dv;
      float gx_r = 0.f;
      if (ln < 32){
        gx_r = __expf(-fmaxf(fmaf(d_cur, tdxd_r, tdxb_r), 0.f));
        if (t < 255){
          const size_t base = (size_t)b2*8192 + (size_t)(t+1)*32 + ln;
          xv = values[base]; mv = masks[base]; dv = deltas[base];
        }
      }
      const int i0 = (2*ln) & 63, i1 = (2*ln+1) & 63;
      const int dw = pkf(__shfl(d_cur, i0), __shfl(d_cur, i1));   // words 0..15 valid
      // aw pack hoisted here (inputs ready; off the serial B->C->D path)
      const int j0 = (2*ln-32) & 63, j1 = (2*ln-31) & 63;
      const float ga  = __shfl(gx_r,  i0), gb  = __shfl(gx_r,  i1);
      const float ma_ = __shfl(m_cur, j0), mb_ = __shfl(m_cur, j1);
      const int aw = (ln < 16) ? pkf(ga, gb) : pkf(ma_, mb_);     // gx|m pairs

      // B: gamma_h (64 rows, K=32, VGPR weights); h *= gamma_h
      {
        float a0 = thb_r, a1 = 0.f;
        #pragma unroll
        for (int g4 = 0; g4 < 4; ++g4){
          const int4 w = fB[g4];
          a0 = dot2(w.x, rl_i(dw, 4*g4+0), a0);
          a1 = dot2(w.y, rl_i(dw, 4*g4+1), a1);
          a0 = dot2(w.z, rl_i(dw, 4*g4+2), a0);
          a1 = dot2(w.w, rl_i(dw, 4*g4+3), a1);
        }
        h_reg *= __expf(-fmaxf(a0+a1, 0.f));
      }
      const int hw = pkf(__shfl(h_reg, i0), __shfl(h_reg, i1));   // h pairs
      // C: x_h (32 rows, K=64, VGPR weights); x_c
      float xh_v = 0.f, x_c_v = 0.f;
      if (ln < 32){
        float a0 = histb_r, a1 = 0.f, a2 = 0.f, a3 = 0.f;
        #pragma unroll
        for (int g4 = 0; g4 < 8; ++g4){
          const int4 w = fC[g4];
          a0 = dot2(w.x, rl_i(hw, 4*g4+0), a0);
          a1 = dot2(w.y, rl_i(hw, 4*g4+1), a1);
          a2 = dot2(w.z, rl_i(hw, 4*g4+2), a2);
          a3 = dot2(w.w, rl_i(hw, 4*g4+3), a3);
        }
        xh_v  = (a0+a1)+(a2+a3);
        x_c_v = m_cur*x_cur + (1.f-m_cur)*xh_v;
      }
      // D: z (fp32 readlane of x_c -- no pack), alpha, c_h, loss, imputation
      float ccv = 0.f;
      if (ln < 32){
        float z0 = featb_r, z1 = 0.f, z2 = 0.f, z3 = 0.f;
        #pragma unroll
        for (int k = 0; k < 32; k += 4){
          z0 = fmaf(rl_f(x_c_v, k+0), wz[k+0], z0);
          z1 = fmaf(rl_f(x_c_v, k+1), wz[k+1], z1);
          z2 = fmaf(rl_f(x_c_v, k+2), wz[k+2], z2);
          z3 = fmaf(rl_f(x_c_v, k+3), wz[k+3], z3);
        }
        const float z = (z0+z1)+(z2+z3);
        float a0 = wcb_r, a1 = 0.f, a2 = 0.f, a3 = 0.f;
        #pragma unroll
        for (int g4 = 0; g4 < 8; ++g4){
          const int4 w = fDa[g4];
          a0 = dot2(w.x, rl_i(aw, 4*g4+0), a0);
          a1 = dot2(w.y, rl_i(aw, 4*g4+1), a1);
          a2 = dot2(w.z, rl_i(aw, 4*g4+2), a2);
          a3 = dot2(w.w, rl_i(aw, 4*g4+3), a3);
        }
        const float al = (a0+a1)+(a2+a3);
        const float ch = al*z + (1.f-al)*xh_v;
        loss_acc += (fabsf(x_cur-xh_v)+fabsf(x_cur-z)+fabsf(x_cur-ch))*m_cur*msum_l[t];
        ccv = m_cur*x_cur + (1.f-m_cur)*ch;
        imps[(size_t)b2*8192 + (size_t)t*32 + ln] = ccv;
      }
      const int ccw = pkf(__shfl(ccv, i0), __shfl(ccv, i1));      // words 0..15
      inp_s[me][ln] = (ln < 16) ? ccw : (ln < 32 ? aw : hw);
    }

    BAR();   // inp_s visible to all waves

    // ---- E: gate GEMM via MFMA; A rows = elems 0..3, rows 4..15 zero ----
    {
      const int arow = ln & 15;
      int4 A[4];
      if (arow < 4){
        #pragma unroll
        for (int ks = 0; ks < 4; ++ks)
          A[ks] = *reinterpret_cast<const int4*>(&inp_s[arow][(ks << 4) + (kg << 2)]);
      } else {
        #pragma unroll
        for (int ks = 0; ks < 4; ++ks) A[ks] = make_int4(0,0,0,0);
      }
      f32x4 acc0 = {bs0, bs0, bs0, bs0};
      f32x4 acc1 = {bs1, bs1, bs1, bs1};
      #pragma unroll
      for (int ks = 0; ks < 4; ++ks){
        acc0 = __builtin_amdgcn_mfma_f32_16x16x32_f16(
                 __builtin_bit_cast(h8, A[ks]), __builtin_bit_cast(h8, Wb[0][ks]), acc0, 0,0,0);
        acc1 = __builtin_amdgcn_mfma_f32_16x16x32_f16(
                 __builtin_bit_cast(h8, A[ks]), __builtin_bit_cast(h8, Wb[1][ks]), acc1, 0,0,0);
      }
      // C/D: col=lane&15, row=(lane>>4)*4+reg -> kg==0 lanes hold rows 0-3
      if (kg == 0){
        #pragma unroll
        for (int e = 0; e < 4; ++e){
          gp[e][col0]      = acc0[e];
          gp[e][col0 + 16] = acc1[e];
        }
      }
    }

    BAR();   // gates visible to chain waves

    // ---- F: LSTM pointwise update (chain waves) ----
    if (chain){
      const float ig = gp[me][ln];
      const float fg = gp[me][64+ln];
      const float gg = gp[me][128+ln];
      const float og = gp[me][192+ln];
      c_reg = fsig(fg)*c_reg + fsig(ig)*ftanh(gg);
      h_reg = fsig(og)*ftanh(c_reg);
    }
  }

  // ---- epilogue: loss reduce + prediction/BCE (chain waves) ----
  if (chain){
    float l = loss_acc;   // nonzero only on ln<32
    l += __shfl_xor(l,16); l += __shfl_xor(l,8);
    l += __shfl_xor(l,4);  l += __shfl_xor(l,2); l += __shfl_xor(l,1);
    if (ln == 0) atomicAdd(xl_acc, l);

    float p = h_reg * out_W[ln];
    p += __shfl_xor(p,32); p += __shfl_xor(p,16); p += __shfl_xor(p,8);
    p += __shfl_xor(p,4);  p += __shfl_xor(p,2);  p += __shfl_xor(p,1);
    if (ln == 0){
      const float y = p + out_b[0];
      predictions[b2] = fsig(y);
      const float lab = labels[b2];
      const float it  = is_train[b2];
      const float mx  = fmaxf(-y, 0.f);
      const float bce = y - y*lab + mx + __logf(__expf(-mx) + __expf(-y - mx));
      atomicAdd(bce_acc, bce * it);
    }
  }
}

// ---------------------------------------------------------------------------
// Kernel 3: finalize loss scalar
// ---------------------------------------------------------------------------
__global__ void final_kernel(const float* __restrict__ is_train,
                             const float* __restrict__ ws,
                             float* __restrict__ out){
  const int tid = threadIdx.x;
  __shared__ float red[256];
  red[tid] = is_train[tid] + is_train[tid+256] + is_train[tid+512] + is_train[tid+768];
  __syncthreads();
  for (int off = 128; off > 0; off >>= 1){
    if (tid < off) red[tid] += red[tid + off];
    __syncthreads();
  }
  if (tid == 0){
    const float yl = ws[1] / (red[0] + EPSF);
    out[0] = ws[0] / 256.0f + 0.1f * yl;
  }
}

extern "C" void kernel_launch(void* const* d_in, const int* in_sizes, int n_in,
                              void* d_out, int out_size, void* d_ws, size_t ws_size,
                              hipStream_t stream){
  const float* values   = (const float*)d_in[0];
  const float* masks    = (const float*)d_in[1];
  const float* deltas   = (const float*)d_in[2];
  const float* labels   = (const float*)d_in[5];
  const float* is_train = (const float*)d_in[6];
  const float* td_h_W   = (const float*)d_in[7];
  const float* td_h_b   = (const float*)d_in[8];
  const float* td_x_W   = (const float*)d_in[9];
  const float* td_x_b   = (const float*)d_in[10];
  const float* hist_W   = (const float*)d_in[11];
  const float* hist_b   = (const float*)d_in[12];
  const float* feat_W   = (const float*)d_in[13];
  const float* feat_b   = (const float*)d_in[14];
  const float* wc_W     = (const float*)d_in[15];
  const float* wc_b     = (const float*)d_in[16];
  const float* W_ih     = (const float*)d_in[17];
  const float* W_hh     = (const float*)d_in[18];
  const float* b_ih     = (const float*)d_in[19];
  const float* b_hh     = (const float*)d_in[20];
  const float* out_W    = (const float*)d_in[21];
  const float* out_b    = (const float*)d_in[22];

  float* out = (float*)d_out;                 // [0]=loss, [1..1025)=preds, [1025..)=imps
  float* ws  = (float*)d_ws;                  // [0]=xl_sum, [1]=bce_sum, [2..258)=msum

  hipMemsetAsync(ws, 0, 2*sizeof(float), stream);
  msum_kernel<<<256, 256, 0, stream>>>(masks, ws + 2);
  rits_kernel<<<256, 512, 0, stream>>>(values, masks, deltas, labels, is_train,
      td_h_W, td_h_b, td_x_W, td_x_b, hist_W, hist_b, feat_W, feat_b,
      wc_W, wc_b, W_ih, W_hh, b_ih, b_hh, out_W, out_b,
      ws + 2, ws + 0, ws + 1, out + 1, out + 1 + 1024);
  final_kernel<<<1, 256, 0, stream>>>(is_train, ws, out);
}

// Round 12
// 449.653 us; speedup vs baseline: 1.7618x; 1.0190x over previous
//
#include <hip/hip_runtime.h>

#define EPSF 1e-5f

typedef _Float16 h2f  __attribute__((ext_vector_type(2)));
typedef _Float16 h8   __attribute__((ext_vector_type(8)));
typedef float    f32x4 __attribute__((ext_vector_type(4)));

#if defined(__has_builtin)
#if __has_builtin(__builtin_amdgcn_fdot2)
#define HAVE_FDOT2 1
#endif
#endif

__device__ __forceinline__ float fsig(float x){ return 1.0f/(1.0f+__expf(-x)); }
__device__ __forceinline__ float ftanh(float x){
  float e = __expf(2.f*x);
  float r = (e-1.f)/(e+1.f);
  return (x > 15.f) ? 1.f : ((x < -15.f) ? -1.f : r);
}
__device__ __forceinline__ int pkf(float lo, float hi){
  return __builtin_bit_cast(int, __builtin_amdgcn_cvt_pkrtz(lo, hi));
}
__device__ __forceinline__ int4 mk4(const float* p){
  return make_int4(pkf(p[0],p[1]),pkf(p[2],p[3]),pkf(p[4],p[5]),pkf(p[6],p[7]));
}
__device__ __forceinline__ float dot2(int w, int x, float acc){
#ifdef HAVE_FDOT2
  return __builtin_amdgcn_fdot2(__builtin_bit_cast(h2f, w),
                                __builtin_bit_cast(h2f, x), acc, false);
#else
  h2f a = __builtin_bit_cast(h2f, w), b = __builtin_bit_cast(h2f, x);
  return acc + (float)a[0]*(float)b[0] + (float)a[1]*(float)b[1];
#endif
}
__device__ __forceinline__ int rl_i(int v, int l){ return __builtin_amdgcn_readlane(v, l); }
__device__ __forceinline__ float rl_f(float v, int l){
  return __int_as_float(__builtin_amdgcn_readlane(__float_as_int(v), l));
}
// light barrier: order LDS only; global loads/stores stay in flight
#define BAR() do{ asm volatile("s_waitcnt lgkmcnt(0)" ::: "memory"); __builtin_amdgcn_s_barrier(); }while(0)

// ---------------------------------------------------------------------------
// Kernel 1: msum[t] = sum_{b,n} masks[b,t,n] + EPS   (one block per t)
// ---------------------------------------------------------------------------
__global__ void msum_kernel(const float* __restrict__ masks, float* __restrict__ msum){
  const int t   = blockIdx.x;
  const int tid = threadIdx.x;
  const int b0  = tid >> 3;
  const int n4  = (tid & 7) << 2;
  float s = 0.f;
  #pragma unroll 4
  for (int i = 0; i < 32; ++i) {
    const int b = b0 + (i << 5);
    const float4 v = *reinterpret_cast<const float4*>(masks + ((size_t)b*256 + t)*32 + n4);
    s += v.x + v.y + v.z + v.w;
  }
  __shared__ float red[256];
  red[tid] = s; __syncthreads();
  for (int off = 128; off > 0; off >>= 1) {
    if (tid < off) red[tid] += red[tid + off];
    __syncthreads();
  }
  if (tid == 0) msum[t] = red[0] + EPSF;
}

// ---------------------------------------------------------------------------
// Kernel 2: persistent RNN. 256 blocks x 512 threads, 4 batch elems / block.
// Round-11 structure unchanged; ONLY delta: amdgpu_waves_per_eu(2,2) grants
// a 256-VGPR/wave budget (block = 2 waves/SIMD, 1 block/CU) so the ~173-reg
// chain waves stop spilling to scratch (r11: VGPR pinned at 128, WRITE_SIZE
// +9MB of spill traffic, per-step scratch reloads on the critical path).
// ---------------------------------------------------------------------------
__global__ __launch_bounds__(512)
__attribute__((amdgpu_waves_per_eu(2, 2)))
void rits_kernel(
  const float* __restrict__ values, const float* __restrict__ masks,
  const float* __restrict__ deltas, const float* __restrict__ labels,
  const float* __restrict__ is_train,
  const float* __restrict__ td_h_W, const float* __restrict__ td_h_b,
  const float* __restrict__ td_x_W, const float* __restrict__ td_x_b,
  const float* __restrict__ hist_W, const float* __restrict__ hist_b,
  const float* __restrict__ feat_W, const float* __restrict__ feat_b,
  const float* __restrict__ wc_W,  const float* __restrict__ wc_b,
  const float* __restrict__ W_ih,  const float* __restrict__ W_hh,
  const float* __restrict__ b_ih,  const float* __restrict__ b_hh,
  const float* __restrict__ out_W, const float* __restrict__ out_b,
  const float* __restrict__ msum,
  float* __restrict__ xl_acc, float* __restrict__ bce_acc,
  float* __restrict__ predictions, float* __restrict__ imps)
{
  // [e][ ccw 0..15 | mw 16..31 | hw 32..63 ] ; stride 84 (84%32=20) ->
  // rows 0..3 land on distinct banks for same-word reads.
  __shared__ __align__(16) int  inp_s[4][84];
  __shared__ float gp[4][256];    // [elem][gate row]
  __shared__ float msum_l[256];   // 1/msum[t]

  const int tid = threadIdx.x;
  const int b   = blockIdx.x;
  const int wv  = tid >> 6;          // 0..7
  const int ln  = tid & 63;
  const bool chain = (wv < 4);
  const int me  = wv & 3;
  const int b2  = (b << 2) | me;

  if (tid < 256) msum_l[tid] = 1.0f / msum[tid];

  // ---- per-thread gate B-fragments (all 8 waves): 2 n-tiles x 4 k-steps ----
  int4 Wb[2][4];
  const int kg = ln >> 4;
  #pragma unroll
  for (int nt = 0; nt < 2; ++nt){
    const int col = (wv << 5) + (nt << 4) + (ln & 15);
    #pragma unroll
    for (int ks = 0; ks < 4; ++ks){
      const int k0 = (ks << 5) + (kg << 3);
      const float* src = (k0 < 64) ? (W_ih + (size_t)col*64 + k0)
                                   : (W_hh + (size_t)col*64 + (k0 - 64));
      Wb[nt][ks] = make_int4(pkf(src[0],src[1]), pkf(src[2],src[3]),
                             pkf(src[4],src[5]), pkf(src[6],src[7]));
    }
  }
  const int col0 = (wv << 5) + (ln & 15);
  const float bs0 = b_ih[col0]      + b_hh[col0];
  const float bs1 = b_ih[col0 + 16] + b_hh[col0 + 16];

  // ---- chain-wave VGPR weights + registers ----
  int4  fB[4];      // td_h_W row ln (K=32)
  int4  fC[8];      // hist_W row (ln&31) (K=64)
  int4  fDa[8];     // wc_W row (ln&31) (K=64, [gx|m])
  float wz[32];     // feat_W row (ln&31), fp32, diag 0
  float thb_r=0.f, tdxd_r=0.f, tdxb_r=0.f, histb_r=0.f, featb_r=0.f, wcb_r=0.f;
  float xv=0.f, mv=0.f, dv=0.f;
  if (chain){
    const int nr = ln & 31;
    #pragma unroll
    for (int g = 0; g < 4; ++g) fB[g] = mk4(td_h_W + ln*32 + 8*g);
    #pragma unroll
    for (int g = 0; g < 8; ++g) fC[g] = mk4(hist_W + nr*64 + 8*g);
    #pragma unroll
    for (int g = 0; g < 8; ++g) fDa[g] = mk4(wc_W + nr*64 + 8*g);
    #pragma unroll
    for (int k = 0; k < 32; ++k) wz[k] = (k==nr) ? 0.f : feat_W[nr*32 + k];
    thb_r = td_h_b[ln];
    if (ln < 32){
      tdxd_r  = td_x_W[ln*33];
      tdxb_r  = td_x_b[ln];
      histb_r = hist_b[ln];
      featb_r = feat_b[ln];
      wcb_r   = wc_b[ln];
      const size_t base = (size_t)b2*8192 + ln;
      xv = values[base]; mv = masks[base]; dv = deltas[base];
    }
  }
  float h_reg = 0.f, c_reg = 0.f, loss_acc = 0.f;

  __syncthreads();

  for (int t = 0; t < 256; ++t){
    // ---- chain A-D ----
    if (chain){
      const float x_cur = xv, m_cur = mv, d_cur = dv;
      float gx_r = 0.f;
      if (ln < 32){
        gx_r = __expf(-fmaxf(fmaf(d_cur, tdxd_r, tdxb_r), 0.f));
        if (t < 255){
          const size_t base = (size_t)b2*8192 + (size_t)(t+1)*32 + ln;
          xv = values[base]; mv = masks[base]; dv = deltas[base];
        }
      }
      const int i0 = (2*ln) & 63, i1 = (2*ln+1) & 63;
      const int dw = pkf(__shfl(d_cur, i0), __shfl(d_cur, i1));   // words 0..15 valid
      // aw pack hoisted here (inputs ready; off the serial B->C->D path)
      const int j0 = (2*ln-32) & 63, j1 = (2*ln-31) & 63;
      const float ga  = __shfl(gx_r,  i0), gb  = __shfl(gx_r,  i1);
      const float ma_ = __shfl(m_cur, j0), mb_ = __shfl(m_cur, j1);
      const int aw = (ln < 16) ? pkf(ga, gb) : pkf(ma_, mb_);     // gx|m pairs

      // B: gamma_h (64 rows, K=32, VGPR weights); h *= gamma_h
      {
        float a0 = thb_r, a1 = 0.f;
        #pragma unroll
        for (int g4 = 0; g4 < 4; ++g4){
          const int4 w = fB[g4];
          a0 = dot2(w.x, rl_i(dw, 4*g4+0), a0);
          a1 = dot2(w.y, rl_i(dw, 4*g4+1), a1);
          a0 = dot2(w.z, rl_i(dw, 4*g4+2), a0);
          a1 = dot2(w.w, rl_i(dw, 4*g4+3), a1);
        }
        h_reg *= __expf(-fmaxf(a0+a1, 0.f));
      }
      const int hw = pkf(__shfl(h_reg, i0), __shfl(h_reg, i1));   // h pairs
      // C: x_h (32 rows, K=64, VGPR weights); x_c
      float xh_v = 0.f, x_c_v = 0.f;
      if (ln < 32){
        float a0 = histb_r, a1 = 0.f, a2 = 0.f, a3 = 0.f;
        #pragma unroll
        for (int g4 = 0; g4 < 8; ++g4){
          const int4 w = fC[g4];
          a0 = dot2(w.x, rl_i(hw, 4*g4+0), a0);
          a1 = dot2(w.y, rl_i(hw, 4*g4+1), a1);
          a2 = dot2(w.z, rl_i(hw, 4*g4+2), a2);
          a3 = dot2(w.w, rl_i(hw, 4*g4+3), a3);
        }
        xh_v  = (a0+a1)+(a2+a3);
        x_c_v = m_cur*x_cur + (1.f-m_cur)*xh_v;
      }
      // D: z (fp32 readlane of x_c -- no pack), alpha, c_h, loss, imputation
      float ccv = 0.f;
      if (ln < 32){
        float z0 = featb_r, z1 = 0.f, z2 = 0.f, z3 = 0.f;
        #pragma unroll
        for (int k = 0; k < 32; k += 4){
          z0 = fmaf(rl_f(x_c_v, k+0), wz[k+0], z0);
          z1 = fmaf(rl_f(x_c_v, k+1), wz[k+1], z1);
          z2 = fmaf(rl_f(x_c_v, k+2), wz[k+2], z2);
          z3 = fmaf(rl_f(x_c_v, k+3), wz[k+3], z3);
        }
        const float z = (z0+z1)+(z2+z3);
        float a0 = wcb_r, a1 = 0.f, a2 = 0.f, a3 = 0.f;
        #pragma unroll
        for (int g4 = 0; g4 < 8; ++g4){
          const int4 w = fDa[g4];
          a0 = dot2(w.x, rl_i(aw, 4*g4+0), a0);
          a1 = dot2(w.y, rl_i(aw, 4*g4+1), a1);
          a2 = dot2(w.z, rl_i(aw, 4*g4+2), a2);
          a3 = dot2(w.w, rl_i(aw, 4*g4+3), a3);
        }
        const float al = (a0+a1)+(a2+a3);
        const float ch = al*z + (1.f-al)*xh_v;
        loss_acc += (fabsf(x_cur-xh_v)+fabsf(x_cur-z)+fabsf(x_cur-ch))*m_cur*msum_l[t];
        ccv = m_cur*x_cur + (1.f-m_cur)*ch;
        imps[(size_t)b2*8192 + (size_t)t*32 + ln] = ccv;
      }
      const int ccw = pkf(__shfl(ccv, i0), __shfl(ccv, i1));      // words 0..15
      inp_s[me][ln] = (ln < 16) ? ccw : (ln < 32 ? aw : hw);
    }

    BAR();   // inp_s visible to all waves

    // ---- E: gate GEMM via MFMA; A rows = elems 0..3, rows 4..15 zero ----
    {
      const int arow = ln & 15;
      int4 A[4];
      if (arow < 4){
        #pragma unroll
        for (int ks = 0; ks < 4; ++ks)
          A[ks] = *reinterpret_cast<const int4*>(&inp_s[arow][(ks << 4) + (kg << 2)]);
      } else {
        #pragma unroll
        for (int ks = 0; ks < 4; ++ks) A[ks] = make_int4(0,0,0,0);
      }
      f32x4 acc0 = {bs0, bs0, bs0, bs0};
      f32x4 acc1 = {bs1, bs1, bs1, bs1};
      #pragma unroll
      for (int ks = 0; ks < 4; ++ks){
        acc0 = __builtin_amdgcn_mfma_f32_16x16x32_f16(
                 __builtin_bit_cast(h8, A[ks]), __builtin_bit_cast(h8, Wb[0][ks]), acc0, 0,0,0);
        acc1 = __builtin_amdgcn_mfma_f32_16x16x32_f16(
                 __builtin_bit_cast(h8, A[ks]), __builtin_bit_cast(h8, Wb[1][ks]), acc1, 0,0,0);
      }
      // C/D: col=lane&15, row=(lane>>4)*4+reg -> kg==0 lanes hold rows 0-3
      if (kg == 0){
        #pragma unroll
        for (int e = 0; e < 4; ++e){
          gp[e][col0]      = acc0[e];
          gp[e][col0 + 16] = acc1[e];
        }
      }
    }

    BAR();   // gates visible to chain waves

    // ---- F: LSTM pointwise update (chain waves) ----
    if (chain){
      const float ig = gp[me][ln];
      const float fg = gp[me][64+ln];
      const float gg = gp[me][128+ln];
      const float og = gp[me][192+ln];
      c_reg = fsig(fg)*c_reg + fsig(ig)*ftanh(gg);
      h_reg = fsig(og)*ftanh(c_reg);
    }
  }

  // ---- epilogue: loss reduce + prediction/BCE (chain waves) ----
  if (chain){
    float l = loss_acc;   // nonzero only on ln<32
    l += __shfl_xor(l,16); l += __shfl_xor(l,8);
    l += __shfl_xor(l,4);  l += __shfl_xor(l,2); l += __shfl_xor(l,1);
    if (ln == 0) atomicAdd(xl_acc, l);

    float p = h_reg * out_W[ln];
    p += __shfl_xor(p,32); p += __shfl_xor(p,16); p += __shfl_xor(p,8);
    p += __shfl_xor(p,4);  p += __shfl_xor(p,2);  p += __shfl_xor(p,1);
    if (ln == 0){
      const float y = p + out_b[0];
      predictions[b2] = fsig(y);
      const float lab = labels[b2];
      const float it  = is_train[b2];
      const float mx  = fmaxf(-y, 0.f);
      const float bce = y - y*lab + mx + __logf(__expf(-mx) + __expf(-y - mx));
      atomicAdd(bce_acc, bce * it);
    }
  }
}

// ---------------------------------------------------------------------------
// Kernel 3: finalize loss scalar
// ---------------------------------------------------------------------------
__global__ void final_kernel(const float* __restrict__ is_train,
                             const float* __restrict__ ws,
                             float* __restrict__ out){
  const int tid = threadIdx.x;
  __shared__ float red[256];
  red[tid] = is_train[tid] + is_train[tid+256] + is_train[tid+512] + is_train[tid+768];
  __syncthreads();
  for (int off = 128; off > 0; off >>= 1){
    if (tid < off) red[tid] += red[tid + off];
    __syncthreads();
  }
  if (tid == 0){
    const float yl = ws[1] / (red[0] + EPSF);
    out[0] = ws[0] / 256.0f + 0.1f * yl;
  }
}

extern "C" void kernel_launch(void* const* d_in, const int* in_sizes, int n_in,
                              void* d_out, int out_size, void* d_ws, size_t ws_size,
                              hipStream_t stream){
  const float* values   = (const float*)d_in[0];
  const float* masks    = (const float*)d_in[1];
  const float* deltas   = (const float*)d_in[2];
  const float* labels   = (const float*)d_in[5];
  const float* is_train = (const float*)d_in[6];
  const float* td_h_W   = (const float*)d_in[7];
  const float* td_h_b   = (const float*)d_in[8];
  const float* td_x_W   = (const float*)d_in[9];
  const float* td_x_b   = (const float*)d_in[10];
  const float* hist_W   = (const float*)d_in[11];
  const float* hist_b   = (const float*)d_in[12];
  const float* feat_W   = (const float*)d_in[13];
  const float* feat_b   = (const float*)d_in[14];
  const float* wc_W     = (const float*)d_in[15];
  const float* wc_b     = (const float*)d_in[16];
  const float* W_ih     = (const float*)d_in[17];
  const float* W_hh     = (const float*)d_in[18];
  const float* b_ih     = (const float*)d_in[19];
  const float* b_hh     = (const float*)d_in[20];
  const float* out_W    = (const float*)d_in[21];
  const float* out_b    = (const float*)d_in[22];

  float* out = (float*)d_out;                 // [0]=loss, [1..1025)=preds, [1025..)=imps
  float* ws  = (float*)d_ws;                  // [0]=xl_sum, [1]=bce_sum, [2..258)=msum

  hipMemsetAsync(ws, 0, 2*sizeof(float), stream);
  msum_kernel<<<256, 256, 0, stream>>>(masks, ws + 2);
  rits_kernel<<<256, 512, 0, stream>>>(values, masks, deltas, labels, is_train,
      td_h_W, td_h_b, td_x_W, td_x_b, hist_W, hist_b, feat_W, feat_b,
      wc_W, wc_b, W_ih, W_hh, b_ih, b_hh, out_W, out_b,
      ws + 2, ws + 0, ws + 1, out + 1, out + 1 + 1024);
  final_kernel<<<1, 256, 0, stream>>>(is_train, ws, out);
}